// Round 6
// baseline (51991.449 us; speedup 1.0000x reference)
//
#include <hip/hip_runtime.h>
#include <math.h>

// Problem constants: S=1024, B=64, I=512, H=512, 2 layers, fp32.
#define SEQ 1024
#define BATCH 64
#define HID 512
#define MROWS (SEQ * BATCH)   // 65536

// Recurrence decomposition
#define SLICES 8              // j-slices per batch group
#define JW 64                 // output columns per block
#define NGROUPS 32            // batch pairs
#define PSTRIDE ((size_t)NGROUPS * SLICES * 2 * JW)   // 32768 u64 slots per parity
#define SPACE (2 * PSTRIDE)   // one signal space (both parities): y0 and y1 each

typedef unsigned long long u64;
typedef unsigned int u32;
typedef float f32x2 __attribute__((ext_vector_type(2)));

// ---------------------------------------------------------------------------
// Transpose W_hh (H,H) row-major (j,k) -> Wt[k*H + j].
// ---------------------------------------------------------------------------
__launch_bounds__(256)
__global__ void transposeW(const float* __restrict__ W, float* __restrict__ Wt) {
    __shared__ float tile[32][33];
    int bx = blockIdx.x % 16;           // col-tile
    int by = blockIdx.x / 16;           // row-tile
    int tx = threadIdx.x % 32;
    int ty = threadIdx.x / 32;          // 0..7
    #pragma unroll
    for (int i = 0; i < 32; i += 8)
        tile[ty + i][tx] = W[(size_t)(by * 32 + ty + i) * HID + bx * 32 + tx];
    __syncthreads();
    #pragma unroll
    for (int i = 0; i < 32; i += 8)
        Wt[(size_t)(bx * 32 + ty + i) * HID + by * 32 + tx] = tile[tx][ty + i];
}

// ---------------------------------------------------------------------------
// C[i,j] = sum_k A[i,k] * W[j,k] + b1[j] + b2[j]
// Tiled fp32 GEMM: 64x64 tile per 256-thread block, BK=16, 4x4 micro-tile.
// ---------------------------------------------------------------------------
#define BM 64
#define BN 64
#define BK 16
__launch_bounds__(256)
__global__ void gemm_bias(const float* __restrict__ A, const float* __restrict__ W,
                          const float* __restrict__ b1, const float* __restrict__ b2,
                          float* __restrict__ C) {
    __shared__ float As[BK][BM + 4];
    __shared__ float Ws[BK][BN + 4];

    const int bj = blockIdx.x % (HID / BN);   // 0..7
    const int bi = blockIdx.x / (HID / BN);   // 0..1023
    const int tid = threadIdx.x;
    const int tx = tid % 16;
    const int ty = tid / 16;
    const int row0 = bi * BM;
    const int col0 = bj * BN;

    const int lr = tid / 4;              // 0..63  (tile row)
    const int lk = (tid % 4) * 4;        // 0,4,8,12 (k offset)

    float acc[4][4] = {};

    for (int k0 = 0; k0 < HID; k0 += BK) {
        float4 av = *(const float4*)(A + (size_t)(row0 + lr) * HID + k0 + lk);
        float4 wv = *(const float4*)(W + (size_t)(col0 + lr) * HID + k0 + lk);
        As[lk + 0][lr] = av.x; As[lk + 1][lr] = av.y;
        As[lk + 2][lr] = av.z; As[lk + 3][lr] = av.w;
        Ws[lk + 0][lr] = wv.x; Ws[lk + 1][lr] = wv.y;
        Ws[lk + 2][lr] = wv.z; Ws[lk + 3][lr] = wv.w;
        __syncthreads();
        #pragma unroll
        for (int k = 0; k < BK; ++k) {
            float4 a = *(const float4*)&As[k][ty * 4];
            float4 w = *(const float4*)&Ws[k][tx * 4];
            acc[0][0] += a.x * w.x; acc[0][1] += a.x * w.y; acc[0][2] += a.x * w.z; acc[0][3] += a.x * w.w;
            acc[1][0] += a.y * w.x; acc[1][1] += a.y * w.y; acc[1][2] += a.y * w.z; acc[1][3] += a.y * w.w;
            acc[2][0] += a.z * w.x; acc[2][1] += a.z * w.y; acc[2][2] += a.z * w.z; acc[2][3] += a.z * w.w;
            acc[3][0] += a.w * w.x; acc[3][1] += a.w * w.y; acc[3][2] += a.w * w.z; acc[3][3] += a.w * w.w;
        }
        __syncthreads();
    }

    #pragma unroll
    for (int c = 0; c < 4; ++c) {
        int col = col0 + tx * 4 + c;
        float bias = b1[col] + b2[col];
        #pragma unroll
        for (int r = 0; r < 4; ++r) {
            C[(size_t)(row0 + ty * 4 + r) * HID + col] = acc[r][c] + bias;
        }
    }
}

// ---------------------------------------------------------------------------
// Fused dual-layer distributed recurrence. Round-4 sync skeleton (2 barriers
// per tick, tagged agent-scope packets, consumer-side tanh, own-slice LDS
// bypass), but ONE tick advances BOTH layers: tick t computes y0[t] (layer 0)
// and y1[t-1] (layer 1, one step behind). 2048 serialized fabric hops -> 1025.
// y0 never goes to global memory; the layer-1 input matvec (W_ih1 . y0) is
// fused in with one tick of slack.
//
// Per block (g,s): W_hh0^T and W_hh1^T slices in registers (32+32/thread);
// W_ih1 slice [64 j][512 k] in LDS, XOR-16B swizzled so the per-lane b128
// reads tile the 32-bank space optimally. Waves = 16 k-chunks of 32; the y0
// chunk is read once and feeds both rec0 and in1 partials.
//
// Slot overwrite safety (both spaces, parity reused every 2 ticks): block X
// publishes tag t+1 only after its tick-(t-1) phase-3 polls of tag t
// succeeded, which requires every group peer to have published tag t, which
// (program order) requires each peer's tick-(t-2) phase-3 consumption of tag
// t-1. Hence no poller of tag t-1 remains when its slot is overwritten.
// ---------------------------------------------------------------------------
__device__ __forceinline__ f32x2 pkfma(float w, f32x2 h, f32x2 a) {
    f32x2 wv = {w, w};
    return __builtin_elementwise_fma(wv, h, a);
}
__device__ __forceinline__ int swz(int row, int kf) {    // kf multiple of 4
    return row * HID + (kf ^ ((row & 7) * 4));           // XOR 16B blocks
}

__launch_bounds__(1024, 4)
__global__ void rnn_fused(const float* __restrict__ U0,   // (S,B,H) = x@Wih0^T + biases
                          const float* __restrict__ Wt0,  // W_hh0^T [k][j]
                          const float* __restrict__ Wt1,  // W_hh1^T [k][j]
                          const float* __restrict__ Wih1, // W_ih1 (H,H) row-major
                          const float* __restrict__ bi1,  // b_ih1
                          const float* __restrict__ bh1,  // b_hh1
                          const float* __restrict__ hx,   // (2,B,H)
                          float* __restrict__ y1,         // (S,B,H) out
                          float* __restrict__ hT0,        // (B,H)
                          float* __restrict__ hT1,        // (B,H)
                          u64* __restrict__ hb)           // [2 spaces][2 par][...]
{
    __shared__ float Wih[64 * HID];                        // 128 KB swizzled
    __shared__ __align__(16) float sc0[16][64], sc1[16][64];  // 8 KB h chunks
    __shared__ __align__(16) f32x2 red0[16][64], redc[16][64];// 16 KB partials
    __shared__ float own0[2][64], own1[2][64];             // 1 KB own-slice

    const int blk = blockIdx.x;
    const int s = blk >> 5;              // slice 0..7
    const int g = blk & 31;              // group 0..31
    const int j0 = s * JW;
    const int b0 = g * 2;
    const int tid = threadIdx.x;
    const int jl = tid & 63;             // lane
    const int kq = tid >> 6;             // wave = k-chunk of 32

    // ---- W_hh slices into registers ----
    float wreg0[32], wreg1[32];
    #pragma unroll
    for (int kk = 0; kk < 32; ++kk) {
        wreg0[kk] = Wt0[(size_t)(kq * 32 + kk) * HID + j0 + jl];
        wreg1[kk] = Wt1[(size_t)(kq * 32 + kk) * HID + j0 + jl];
    }

    // ---- W_ih1 slice into swizzled LDS ----
    #pragma unroll
    for (int u = 0; u < 8; ++u) {
        const int kf = kq * 32 + u * 4;
        float4 wv = *(const float4*)(Wih1 + (size_t)(j0 + jl) * HID + kf);
        *(float4*)&Wih[swz(jl, kf)] = wv;
    }

    // ---- gather identity: lane owns h-value (gk, gb) ----
    const int gk = kq * 32 + (jl >> 1);
    const int gb = jl & 1;
    const size_t gslot = (((size_t)g * SLICES + (gk >> 6)) * 2 + gb) * JW + (gk & 63);
    const bool ownw = ((kq >> 1) == s);   // wave's k-range == own j-slice

    // ---- init hidden chunks ----
    sc0[kq][jl] = hx[(size_t)(b0 + gb) * HID + gk];
    sc1[kq][jl] = hx[(size_t)(BATCH + b0 + gb) * HID + gk];

    // ---- producer identity (tid < 128 = waves 0,1) ----
    const int rb = (tid >> 6) & 1;
    const int rj = tid & 63;
    const size_t sbase = (((size_t)g * SLICES + s) * 2 + rb) * JW + rj;
    float u_cur = 0.f, bias1 = 0.f;
    if (tid < 128) {
        u_cur = U0[((size_t)0 * BATCH + (b0 + rb)) * HID + j0 + rj];
        bias1 = bi1[j0 + rj] + bh1[j0 + rj];
    }
    __syncthreads();   // Wih + scratch init visible

    for (int t = 0; t <= SEQ; ++t) {
        const int p = (t + 1) & 1;
        const u32 tag = (u32)(t + 1);

        // prefetch next U0 row (full tick of slack -> hidden)
        float u_nxt = 0.f;
        if (tid < 128 && t + 1 < SEQ)
            u_nxt = U0[((size_t)(t + 1) * BATCH + (b0 + rb)) * HID + j0 + rj];

        // ---- phase 1: 3 partial matvecs (rec0 / in1 / rec1) ----
        f32x2 a0 = {0.f, 0.f}, ac = {0.f, 0.f};
        const float4* h0p = (const float4*)sc0[kq];
        const float4* h1p = (const float4*)sc1[kq];
        #pragma unroll
        for (int u = 0; u < 8; ++u) {
            const float4 wv = *(const float4*)&Wih[swz(jl, kq * 32 + u * 4)];
            const float4 hA = h0p[2 * u], hB = h0p[2 * u + 1];
            const float4 gA = h1p[2 * u], gB = h1p[2 * u + 1];
            const f32x2 xA = {hA.x, hA.y}, xB = {hA.z, hA.w};
            const f32x2 xC = {hB.x, hB.y}, xD = {hB.z, hB.w};
            const f32x2 yA = {gA.x, gA.y}, yB = {gA.z, gA.w};
            const f32x2 yC = {gB.x, gB.y}, yD = {gB.z, gB.w};
            a0 = pkfma(wreg0[4 * u + 0], xA, a0);
            a0 = pkfma(wreg0[4 * u + 1], xB, a0);
            a0 = pkfma(wreg0[4 * u + 2], xC, a0);
            a0 = pkfma(wreg0[4 * u + 3], xD, a0);
            ac = pkfma(wv.x, xA, ac);
            ac = pkfma(wv.y, xB, ac);
            ac = pkfma(wv.z, xC, ac);
            ac = pkfma(wv.w, xD, ac);
            ac = pkfma(wreg1[4 * u + 0], yA, ac);
            ac = pkfma(wreg1[4 * u + 1], yB, ac);
            ac = pkfma(wreg1[4 * u + 2], yC, ac);
            ac = pkfma(wreg1[4 * u + 3], yD, ac);
        }
        if (t < SEQ)  red0[kq][jl] = a0;
        if (t >= 1)   redc[kq][jl] = ac;
        __syncthreads();

        // ---- phase 2 (producer waves): reduce, publish pre-tanh, outputs ----
        if (tid < 128) {
            if (t < SEQ) {   // layer 0 step t
                float s0 = 0.f;
                const float* rp = (const float*)red0;
                #pragma unroll
                for (int q = 0; q < 16; ++q) s0 += rp[(q * 64 + rj) * 2 + rb];
                const float pre0 = u_cur + s0;
                const u64 pkt = ((u64)__float_as_uint(pre0) << 32) | tag;
                __hip_atomic_store(hb + p * PSTRIDE + sbase, pkt,
                                   __ATOMIC_RELAXED, __HIP_MEMORY_SCOPE_AGENT);
                const float v0 = tanhf(pre0);
                own0[rb][rj] = v0;
                if (t == SEQ - 1) hT0[(size_t)(b0 + rb) * HID + j0 + rj] = v0;
            }
            if (t >= 1) {    // layer 1 step t-1
                float s1 = 0.f;
                const float* rp = (const float*)redc;
                #pragma unroll
                for (int q = 0; q < 16; ++q) s1 += rp[(q * 64 + rj) * 2 + rb];
                const float pre1 = bias1 + s1;
                const float v1 = tanhf(pre1);
                y1[((size_t)(t - 1) * BATCH + (b0 + rb)) * HID + j0 + rj] = v1;
                if (t < SEQ) {
                    const u64 pkt = ((u64)__float_as_uint(pre1) << 32) | tag;
                    __hip_atomic_store(hb + SPACE + p * PSTRIDE + sbase, pkt,
                                       __ATOMIC_RELAXED, __HIP_MEMORY_SCOPE_AGENT);
                    own1[rb][rj] = v1;
                }
                if (t == SEQ) hT1[(size_t)(b0 + rb) * HID + j0 + rj] = v1;
            }
            u_cur = u_nxt;
        }
        __syncthreads();

        // ---- phase 3: gather h chunks for next tick ----
        if (t < SEQ) {
            const bool need1 = (t >= 1);
            float v0n, v1n = 0.f;
            if (ownw) {
                v0n = own0[gb][gk & 63];
                if (need1) v1n = own1[gb][gk & 63];
            } else {
                const u64* s0p = hb + p * PSTRIDE + gslot;
                const u64* s1p = hb + SPACE + p * PSTRIDE + gslot;
                u64 pk0 = 0, pk1 = 0;
                bool d0 = false, d1 = !need1;
                int it = 0;
                do {
                    if (!d0) { pk0 = __hip_atomic_load(s0p, __ATOMIC_RELAXED,
                                                       __HIP_MEMORY_SCOPE_AGENT);
                               d0 = ((u32)pk0 == tag); }
                    if (!d1) { pk1 = __hip_atomic_load(s1p, __ATOMIC_RELAXED,
                                                       __HIP_MEMORY_SCOPE_AGENT);
                               d1 = ((u32)pk1 == tag); }
                } while ((!d0 || !d1) && ++it < (1 << 15));   // bounded, no hang
                v0n = tanhf(__uint_as_float((u32)(pk0 >> 32)));
                if (need1) v1n = tanhf(__uint_as_float((u32)(pk1 >> 32)));
            }
            sc0[kq][jl] = v0n;              // same-wave write->read, ds-ordered
            if (need1) sc1[kq][jl] = v1n;
        }
    }
}

// ---------------------------------------------------------------------------
// Launch
// ---------------------------------------------------------------------------
extern "C" void kernel_launch(void* const* d_in, const int* in_sizes, int n_in,
                              void* d_out, int out_size, void* d_ws, size_t ws_size,
                              hipStream_t stream) {
    (void)in_sizes; (void)n_in; (void)out_size; (void)ws_size;

    const float* x      = (const float*)d_in[0];   // (S,B,I)
    const float* hx     = (const float*)d_in[1];   // (2,B,H)
    const float* W_ih0  = (const float*)d_in[2];   // (H,I)
    const float* W_hh0  = (const float*)d_in[3];   // (H,H)
    const float* b_ih0  = (const float*)d_in[4];   // (H,)
    const float* b_hh0  = (const float*)d_in[5];   // (H,)
    const float* W_ih1  = (const float*)d_in[6];   // (H,H)
    const float* W_hh1  = (const float*)d_in[7];   // (H,H)
    const float* b_ih1  = (const float*)d_in[8];   // (H,)
    const float* b_hh1  = (const float*)d_in[9];   // (H,)

    float* out = (float*)d_out;
    float* y1   = out;                                  // (S,B,H)
    float* hT0  = out + (size_t)SEQ * BATCH * HID;      // (B,H)
    float* hT1  = hT0 + (size_t)BATCH * HID;            // (B,H)

    // Workspace: Wt0 (1MB) | Wt1 (1MB) | hb (1MB: 2 spaces x 2 par) | U0 (128MB)
    float* Wt0 = (float*)d_ws;
    float* Wt1 = Wt0 + (size_t)HID * HID;
    u64* hb = (u64*)(Wt1 + (size_t)HID * HID);
    float* U0 = (float*)(hb + 2 * SPACE);

    // zero both slot spaces every launch (tag 0 never matches; agent-scope
    // stores write through -> no stale dirty-line ABA across timed runs)
    hipMemsetAsync(hb, 0, 2 * SPACE * sizeof(u64), stream);

    // 1. transpose W_hh for both layers
    transposeW<<<256, 256, 0, stream>>>(W_hh0, Wt0);
    transposeW<<<256, 256, 0, stream>>>(W_hh1, Wt1);

    // 2. Layer 0 input GEMM: U0 = x @ W_ih0^T + b_ih0 + b_hh0
    gemm_bias<<<(MROWS / BM) * (HID / BN), 256, 0, stream>>>(x, W_ih0, b_ih0, b_hh0, U0);

    // 3. Fused dual-layer recurrence (y0 never hits HBM; no layer-1 GEMM)
    rnn_fused<<<NGROUPS * SLICES, 1024, 0, stream>>>(
        U0, Wt0, Wt1, W_ih1, b_ih1, b_hh1, hx, y1, hT0, hT1, hb);
}

// Round 7
// 11294.236 us; speedup vs baseline: 4.6034x; 4.6034x over previous
//
#include <hip/hip_runtime.h>
#include <math.h>

// Problem constants: S=1024, B=64, I=512, H=512, 2 layers, fp32.
#define SEQ 1024
#define BATCH 64
#define HID 512
#define MROWS (SEQ * BATCH)   // 65536

// Recurrence decomposition: 16 groups x 4 batch, 16 slices x 32 cols.
#define SLICES 16
#define JW 32
#define NGROUPS 16
#define NB 4
#define PSTRIDE ((size_t)NGROUPS * SLICES * 128)   // 32768 u64 slots per parity
#define SPACE (2 * PSTRIDE)                        // one signal space (2 parities)

typedef unsigned long long u64;
typedef unsigned int u32;
typedef float f32x4 __attribute__((ext_vector_type(4)));

// ---------------------------------------------------------------------------
// Transpose W_hh (H,H) row-major (j,k) -> Wt[k*H + j].
// ---------------------------------------------------------------------------
__launch_bounds__(256)
__global__ void transposeW(const float* __restrict__ W, float* __restrict__ Wt) {
    __shared__ float tile[32][33];
    int bx = blockIdx.x % 16;           // col-tile
    int by = blockIdx.x / 16;           // row-tile
    int tx = threadIdx.x % 32;
    int ty = threadIdx.x / 32;          // 0..7
    #pragma unroll
    for (int i = 0; i < 32; i += 8)
        tile[ty + i][tx] = W[(size_t)(by * 32 + ty + i) * HID + bx * 32 + tx];
    __syncthreads();
    #pragma unroll
    for (int i = 0; i < 32; i += 8)
        Wt[(size_t)(bx * 32 + ty + i) * HID + by * 32 + tx] = tile[tx][ty + i];
}

// ---------------------------------------------------------------------------
// C[i,j] = sum_k A[i,k] * W[j,k] + b1[j] + b2[j]
// Tiled fp32 GEMM: 64x64 tile per 256-thread block, BK=16, 4x4 micro-tile.
// ---------------------------------------------------------------------------
#define BM 64
#define BN 64
#define BK 16
__launch_bounds__(256)
__global__ void gemm_bias(const float* __restrict__ A, const float* __restrict__ W,
                          const float* __restrict__ b1, const float* __restrict__ b2,
                          float* __restrict__ C) {
    __shared__ float As[BK][BM + 4];
    __shared__ float Ws[BK][BN + 4];

    const int bj = blockIdx.x % (HID / BN);   // 0..7
    const int bi = blockIdx.x / (HID / BN);   // 0..1023
    const int tid = threadIdx.x;
    const int tx = tid % 16;
    const int ty = tid / 16;
    const int row0 = bi * BM;
    const int col0 = bj * BN;

    const int lr = tid / 4;              // 0..63  (tile row)
    const int lk = (tid % 4) * 4;        // 0,4,8,12 (k offset)

    float acc[4][4] = {};

    for (int k0 = 0; k0 < HID; k0 += BK) {
        float4 av = *(const float4*)(A + (size_t)(row0 + lr) * HID + k0 + lk);
        float4 wv = *(const float4*)(W + (size_t)(col0 + lr) * HID + k0 + lk);
        As[lk + 0][lr] = av.x; As[lk + 1][lr] = av.y;
        As[lk + 2][lr] = av.z; As[lk + 3][lr] = av.w;
        Ws[lk + 0][lr] = wv.x; Ws[lk + 1][lr] = wv.y;
        Ws[lk + 2][lr] = wv.z; Ws[lk + 3][lr] = wv.w;
        __syncthreads();
        #pragma unroll
        for (int k = 0; k < BK; ++k) {
            float4 a = *(const float4*)&As[k][ty * 4];
            float4 w = *(const float4*)&Ws[k][tx * 4];
            acc[0][0] += a.x * w.x; acc[0][1] += a.x * w.y; acc[0][2] += a.x * w.z; acc[0][3] += a.x * w.w;
            acc[1][0] += a.y * w.x; acc[1][1] += a.y * w.y; acc[1][2] += a.y * w.z; acc[1][3] += a.y * w.w;
            acc[2][0] += a.z * w.x; acc[2][1] += a.z * w.y; acc[2][2] += a.z * w.z; acc[2][3] += a.z * w.w;
            acc[3][0] += a.w * w.x; acc[3][1] += a.w * w.y; acc[3][2] += a.w * w.z; acc[3][3] += a.w * w.w;
        }
        __syncthreads();
    }

    #pragma unroll
    for (int c = 0; c < 4; ++c) {
        int col = col0 + tx * 4 + c;
        float bias = b1[col] + b2[col];
        #pragma unroll
        for (int r = 0; r < 4; ++r) {
            C[(size_t)(row0 + ty * 4 + r) * HID + col] = acc[r][c] + bias;
        }
    }
}

// ---------------------------------------------------------------------------
// Fused dual-layer recurrence, register-safe geometry.
// Grid 256 = 16 groups (4 batch each) x 16 slices (32 cols). 1024 thr = 16 waves.
// Per tick t: layer-0 step t and layer-1 step t-1 advance together.
//   phase 1: thread (wave kq, lane jl) = (k-range 16, col j) computes f32x4
//            partials for rec0 (wreg0, regs) and in1+rec1 (Wih LDS + wreg1).
//   barrier A; phase 2: waves 0-1 reduce+publish y0 (pre-tanh, tag t+1);
//            waves 2-3 reduce+publish h1 + store y1 output. barrier B.
//   phase 3: EVERY thread polls its 4 tagged packets (k, b-pair) x {y0,h1}
//            (own-slice packets included - they arrive L2-fast), tanh's,
//            writes LDS state. Poller and phase-1 reader share k>>5 == wave,
//            so all state writes are same-wave: 2 barriers/tick total.
// Register budget: 16+16 weights + 8 acc + temps ~= 75 < 128 cap (1 blk/CU).
// Slot overwrite safety (parity 2, exact-tag): block X publishes tag t+1 only
// after consuming tag t from ALL slices (phase 3 of tick t-1), and any peer Z
// published tag t only after ITS phase-3 consumption of tag t-1. So when X
// overwrites tag t-1 -> t+1, every consumer of t-1 is already done.
// ---------------------------------------------------------------------------
__device__ __forceinline__ f32x4 pkfma4(float w, f32x4 h, f32x4 a) {
    f32x4 wv = {w, w, w, w};
    return __builtin_elementwise_fma(wv, h, a);
}
__device__ __forceinline__ int swz(int row, int kf) {    // kf multiple of 4
    return row * HID + (kf ^ ((row & 7) * 4));           // XOR 16B blocks
}
__device__ __forceinline__ u64 pload(const u64* p) {
    return __hip_atomic_load(p, __ATOMIC_RELAXED, __HIP_MEMORY_SCOPE_AGENT);
}

__launch_bounds__(1024)
__global__ void rnn_fused2(const float* __restrict__ U0,   // (S,B,H) x@Wih0^T+biases
                           const float* __restrict__ Wt0,  // W_hh0^T [k][j]
                           const float* __restrict__ Wt1,  // W_hh1^T [k][j]
                           const float* __restrict__ Wih1, // W_ih1 (H,H) row-major
                           const float* __restrict__ bi1,
                           const float* __restrict__ bh1,
                           const float* __restrict__ hx,   // (2,B,H)
                           float* __restrict__ y1,         // (S,B,H) out
                           float* __restrict__ hT0,        // (B,H)
                           float* __restrict__ hT1,        // (B,H)
                           u64* __restrict__ hb)           // zeroed per launch
{
    __shared__ float Wih[JW * HID];                  // 64 KB swizzled [j][k^]
    __shared__ __align__(16) float scy[HID][NB];     // 8 KB: h0 state (tanh'd)
    __shared__ __align__(16) float sch[HID][NB];     // 8 KB: h1 state
    __shared__ __align__(16) f32x4 red0[32][33];     // ~17 KB padded partials
    __shared__ __align__(16) f32x4 redc[32][33];     // ~17 KB

    const int blk = blockIdx.x;
    const int g = blk & 15;              // group (16 blocks share blk%16 -> XCD-pairs)
    const int s = blk >> 4;              // slice 0..15
    const int j0 = s * JW;
    const int b0 = g * NB;
    const int tid = threadIdx.x;
    const int jl = tid & 63;
    const int kq = tid >> 6;             // wave 0..15
    const int j  = jl & 31;              // weight column within slice
    const int kh = jl >> 5;              // k-half
    const int kbase = kq * 32 + kh * 16; // 16-k range of this thread

    // ---- W_hh slices into registers (16 + 16 per thread) ----
    float w0r[16], w1r[16];
    #pragma unroll
    for (int kk = 0; kk < 16; ++kk) {
        w0r[kk] = Wt0[(size_t)(kbase + kk) * HID + j0 + j];
        w1r[kk] = Wt1[(size_t)(kbase + kk) * HID + j0 + j];
    }
    // ---- W_ih1 slice into swizzled LDS (16 floats per thread) ----
    #pragma unroll
    for (int i = 0; i < 4; ++i) {
        const int kf = kbase + 4 * i;
        float4 wv = *(const float4*)(Wih1 + (size_t)(j0 + j) * HID + kf);
        *(float4*)&Wih[swz(j, kf)] = wv;
    }

    // ---- poll identity: thread owns (k = kq*32 + jl/2, batches pb,pb+1) ----
    const int pk = kq * 32 + (jl >> 1);
    const int pb = 2 * (jl & 1);
    const size_t psl = ((size_t)g * SLICES + kq) * 128 + pb * 32 + (jl >> 1);

    // ---- init LDS state from hx (same-wave mapping as phase 3) ----
    {
        float2 a, c;
        a.x = hx[(size_t)(b0 + pb) * HID + pk];
        a.y = hx[(size_t)(b0 + pb + 1) * HID + pk];
        c.x = hx[(size_t)(BATCH + b0 + pb) * HID + pk];
        c.y = hx[(size_t)(BATCH + b0 + pb + 1) * HID + pk];
        *(float2*)&scy[pk][pb] = a;
        *(float2*)&sch[pk][pb] = c;
    }

    // ---- producer identity (waves 0-3) ----
    const bool isprod = (tid < 256);
    const int pl  = tid >> 7;            // 0: layer 0 (tid<128), 1: layer 1
    const int pj  = tid & 31;
    const int pbb = (tid >> 5) & 3;
    float bias1 = 0.f;
    if (isprod && pl == 1) bias1 = bi1[j0 + pj] + bh1[j0 + pj];
    __syncthreads();

    for (int t = 0; t <= SEQ; ++t) {
        const int p = (t + 1) & 1;
        const u32 tag = (u32)(t + 1);

        // producer prefetch of U0[t] (consumed after barrier A -> hidden)
        float u_cur = 0.f;
        if (isprod && pl == 0 && t < SEQ)
            u_cur = U0[((size_t)t * BATCH + (b0 + pbb)) * HID + j0 + pj];

        // ---- phase 1: partials over 16 k's x 4 batches ----
        f32x4 a0 = {0.f, 0.f, 0.f, 0.f};
        f32x4 ac = {0.f, 0.f, 0.f, 0.f};
        #pragma unroll
        for (int i = 0; i < 4; ++i) {
            const float4 wv = *(const float4*)&Wih[swz(j, kbase + 4 * i)];
            #pragma unroll
            for (int u = 0; u < 4; ++u) {
                const int k = kbase + 4 * i + u;
                const f32x4 hy = *(const f32x4*)&scy[k][0];   // broadcast read
                const f32x4 hh = *(const f32x4*)&sch[k][0];
                const float wi = (u == 0) ? wv.x : (u == 1) ? wv.y
                               : (u == 2) ? wv.z : wv.w;
                a0 = pkfma4(w0r[4 * i + u], hy, a0);
                ac = pkfma4(wi,             hy, ac);
                ac = pkfma4(w1r[4 * i + u], hh, ac);
            }
        }
        red0[2 * kq + kh][j] = a0;
        redc[2 * kq + kh][j] = ac;
        __syncthreads();   // A

        // ---- phase 2 (waves 0-3): reduce + publish pre-tanh + outputs ----
        if (isprod) {
            float sum = 0.f;
            if (pl == 0) {
                #pragma unroll
                for (int q = 0; q < 32; ++q)
                    sum += ((const float*)&red0[q][pj])[pbb];
                if (t < SEQ) {
                    const float pre = u_cur + sum;
                    const u64 pkt = ((u64)__float_as_uint(pre) << 32) | tag;
                    __hip_atomic_store(hb + p * PSTRIDE
                                          + ((size_t)g * SLICES + s) * 128 + pbb * 32 + pj,
                                       pkt, __ATOMIC_RELAXED, __HIP_MEMORY_SCOPE_AGENT);
                    if (t == SEQ - 1)
                        hT0[(size_t)(b0 + pbb) * HID + j0 + pj] = tanhf(pre);
                }
            } else {
                #pragma unroll
                for (int q = 0; q < 32; ++q)
                    sum += ((const float*)&redc[q][pj])[pbb];
                if (t >= 1) {
                    const float pre = bias1 + sum;
                    const float v = tanhf(pre);
                    y1[((size_t)(t - 1) * BATCH + (b0 + pbb)) * HID + j0 + pj] = v;
                    if (t < SEQ) {
                        const u64 pkt = ((u64)__float_as_uint(pre) << 32) | tag;
                        __hip_atomic_store(hb + SPACE + p * PSTRIDE
                                              + ((size_t)g * SLICES + s) * 128 + pbb * 32 + pj,
                                           pkt, __ATOMIC_RELAXED, __HIP_MEMORY_SCOPE_AGENT);
                    }
                    if (t == SEQ)
                        hT1[(size_t)(b0 + pbb) * HID + j0 + pj] = v;
                }
            }
        }
        __syncthreads();   // B

        // ---- phase 3: every thread polls its 4 packets (tag = flag) ----
        if (t < SEQ) {
            const u64* s0 = hb + p * PSTRIDE + psl;          // y0: (pk,pb),(pk,pb+1)
            const u64* s1 = hb + SPACE + p * PSTRIDE + psl;  // h1: same
            const bool need1 = (t >= 1);
            u64 k00 = 0, k01 = 0, k10 = 0, k11 = 0;
            bool d0 = false, d1 = false, d2 = !need1, d3 = !need1;
            int it = 0;
            do {
                if (!d0) { k00 = pload(s0);      d0 = ((u32)k00 == tag); }
                if (!d1) { k01 = pload(s0 + 32); d1 = ((u32)k01 == tag); }
                if (!d2) { k10 = pload(s1);      d2 = ((u32)k10 == tag); }
                if (!d3) { k11 = pload(s1 + 32); d3 = ((u32)k11 == tag); }
            } while (!(d0 && d1 && d2 && d3) && ++it < (1 << 15));  // no hang
            *(float2*)&scy[pk][pb] =
                make_float2(tanhf(__uint_as_float((u32)(k00 >> 32))),
                            tanhf(__uint_as_float((u32)(k01 >> 32))));
            if (need1)
                *(float2*)&sch[pk][pb] =
                    make_float2(tanhf(__uint_as_float((u32)(k10 >> 32))),
                                tanhf(__uint_as_float((u32)(k11 >> 32))));
        }
    }
}

// ---------------------------------------------------------------------------
// Launch
// ---------------------------------------------------------------------------
extern "C" void kernel_launch(void* const* d_in, const int* in_sizes, int n_in,
                              void* d_out, int out_size, void* d_ws, size_t ws_size,
                              hipStream_t stream) {
    (void)in_sizes; (void)n_in; (void)out_size; (void)ws_size;

    const float* x      = (const float*)d_in[0];   // (S,B,I)
    const float* hx     = (const float*)d_in[1];   // (2,B,H)
    const float* W_ih0  = (const float*)d_in[2];   // (H,I)
    const float* W_hh0  = (const float*)d_in[3];   // (H,H)
    const float* b_ih0  = (const float*)d_in[4];   // (H,)
    const float* b_hh0  = (const float*)d_in[5];   // (H,)
    const float* W_ih1  = (const float*)d_in[6];   // (H,H)
    const float* W_hh1  = (const float*)d_in[7];   // (H,H)
    const float* b_ih1  = (const float*)d_in[8];   // (H,)
    const float* b_hh1  = (const float*)d_in[9];   // (H,)

    float* out = (float*)d_out;
    float* y1   = out;                                  // (S,B,H)
    float* hT0  = out + (size_t)SEQ * BATCH * HID;      // (B,H)
    float* hT1  = hT0 + (size_t)BATCH * HID;            // (B,H)

    // Workspace: Wt0 (1MB) | Wt1 (1MB) | hb (1MB) | U0 (128MB)
    float* Wt0 = (float*)d_ws;
    float* Wt1 = Wt0 + (size_t)HID * HID;
    u64* hb = (u64*)(Wt1 + (size_t)HID * HID);
    float* U0 = (float*)(hb + 2 * SPACE);

    // zero both slot spaces every launch (tag 0 never matches; agent-scope
    // stores write through -> no stale dirty-line ABA across timed runs)
    hipMemsetAsync(hb, 0, 2 * SPACE * sizeof(u64), stream);

    // 1. transpose W_hh for both layers
    transposeW<<<256, 256, 0, stream>>>(W_hh0, Wt0);
    transposeW<<<256, 256, 0, stream>>>(W_hh1, Wt1);

    // 2. Layer 0 input GEMM: U0 = x @ W_ih0^T + b_ih0 + b_hh0
    gemm_bias<<<(MROWS / BM) * (HID / BN), 256, 0, stream>>>(x, W_ih0, b_ih0, b_hh0, U0);

    // 3. Fused dual-layer recurrence (y0 never hits HBM; no layer-1 GEMM)
    rnn_fused2<<<NGROUPS * SLICES, 1024, 0, stream>>>(
        U0, Wt0, Wt1, W_ih1, b_ih1, b_hh1, hx, y1, hT0, hT1, hb);
}

// Round 8
// 11220.486 us; speedup vs baseline: 4.6336x; 1.0066x over previous
//
#include <hip/hip_runtime.h>
#include <math.h>

// Problem constants: S=1024, B=64, I=512, H=512, 2 layers, fp32.
#define SEQ 1024
#define BATCH 64
#define HID 512
#define MROWS (SEQ * BATCH)   // 65536

// Recurrence decomposition: 16 groups x 4 batch, 16 slices x 32 cols.
#define SLICES 16
#define JW 32
#define NGROUPS 16
#define NB 4
#define PSTRIDE ((size_t)NGROUPS * SLICES * 128)   // 32768 u64 slots per parity
#define SPACE (2 * PSTRIDE)                        // one signal space (2 parities)

typedef unsigned long long u64;
typedef unsigned int u32;
typedef float f32x4 __attribute__((ext_vector_type(4)));

// ---------------------------------------------------------------------------
// Transpose W_hh (H,H) row-major (j,k) -> Wt[k*H + j].
// ---------------------------------------------------------------------------
__launch_bounds__(256)
__global__ void transposeW(const float* __restrict__ W, float* __restrict__ Wt) {
    __shared__ float tile[32][33];
    int bx = blockIdx.x % 16;           // col-tile
    int by = blockIdx.x / 16;           // row-tile
    int tx = threadIdx.x % 32;
    int ty = threadIdx.x / 32;          // 0..7
    #pragma unroll
    for (int i = 0; i < 32; i += 8)
        tile[ty + i][tx] = W[(size_t)(by * 32 + ty + i) * HID + bx * 32 + tx];
    __syncthreads();
    #pragma unroll
    for (int i = 0; i < 32; i += 8)
        Wt[(size_t)(bx * 32 + ty + i) * HID + by * 32 + tx] = tile[tx][ty + i];
}

// ---------------------------------------------------------------------------
// C[i,j] = sum_k A[i,k] * W[j,k] + b1[j] + b2[j]
// Tiled fp32 GEMM: 64x64 tile per 256-thread block, BK=16, 4x4 micro-tile.
// ---------------------------------------------------------------------------
#define BM 64
#define BN 64
#define BK 16
__launch_bounds__(256)
__global__ void gemm_bias(const float* __restrict__ A, const float* __restrict__ W,
                          const float* __restrict__ b1, const float* __restrict__ b2,
                          float* __restrict__ C) {
    __shared__ float As[BK][BM + 4];
    __shared__ float Ws[BK][BN + 4];

    const int bj = blockIdx.x % (HID / BN);   // 0..7
    const int bi = blockIdx.x / (HID / BN);   // 0..1023
    const int tid = threadIdx.x;
    const int tx = tid % 16;
    const int ty = tid / 16;
    const int row0 = bi * BM;
    const int col0 = bj * BN;

    const int lr = tid / 4;              // 0..63  (tile row)
    const int lk = (tid % 4) * 4;        // 0,4,8,12 (k offset)

    float acc[4][4] = {};

    for (int k0 = 0; k0 < HID; k0 += BK) {
        float4 av = *(const float4*)(A + (size_t)(row0 + lr) * HID + k0 + lk);
        float4 wv = *(const float4*)(W + (size_t)(col0 + lr) * HID + k0 + lk);
        As[lk + 0][lr] = av.x; As[lk + 1][lr] = av.y;
        As[lk + 2][lr] = av.z; As[lk + 3][lr] = av.w;
        Ws[lk + 0][lr] = wv.x; Ws[lk + 1][lr] = wv.y;
        Ws[lk + 2][lr] = wv.z; Ws[lk + 3][lr] = wv.w;
        __syncthreads();
        #pragma unroll
        for (int k = 0; k < BK; ++k) {
            float4 a = *(const float4*)&As[k][ty * 4];
            float4 w = *(const float4*)&Ws[k][tx * 4];
            acc[0][0] += a.x * w.x; acc[0][1] += a.x * w.y; acc[0][2] += a.x * w.z; acc[0][3] += a.x * w.w;
            acc[1][0] += a.y * w.x; acc[1][1] += a.y * w.y; acc[1][2] += a.y * w.z; acc[1][3] += a.y * w.w;
            acc[2][0] += a.z * w.x; acc[2][1] += a.z * w.y; acc[2][2] += a.z * w.z; acc[2][3] += a.z * w.w;
            acc[3][0] += a.w * w.x; acc[3][1] += a.w * w.y; acc[3][2] += a.w * w.z; acc[3][3] += a.w * w.w;
        }
        __syncthreads();
    }

    #pragma unroll
    for (int c = 0; c < 4; ++c) {
        int col = col0 + tx * 4 + c;
        float bias = b1[col] + b2[col];
        #pragma unroll
        for (int r = 0; r < 4; ++r) {
            C[(size_t)(row0 + ty * 4 + r) * HID + col] = acc[r][c] + bias;
        }
    }
}

// ---------------------------------------------------------------------------
// Fused dual-layer recurrence. IDENTICAL structure to the passing round-7
// kernel; the only functional change is amdgpu_waves_per_eu(4,4), which pins
// the occupancy target to the LDS-forced reality (1 block/CU = 4 waves/EU)
// and raises the VGPR budget 64 -> 128, eliminating the ~19-reg weight spill
// that cost 19.2 MB/tick of HBM scratch re-reads (the entire 25K-cycle tick).
//
// Grid 256 = 16 groups (4 batch each) x 16 slices (32 cols). 1024 thr = 16 waves.
// Per tick t: layer-0 step t and layer-1 step t-1 advance together.
//   phase 1: thread (wave kq, lane jl) = (16-k range, col j) computes f32x4
//            partials for rec0 (w0r regs) and in1+rec1 (Wih LDS + w1r regs).
//   barrier A; phase 2: waves 0-1 reduce+publish y0 (pre-tanh, tag t+1);
//            waves 2-3 reduce+publish h1 + store y1 output. barrier B.
//   phase 3: EVERY thread polls its 4 tagged packets (k, b-pair) x {y0,h1},
//            tanh's, writes LDS state. Poller and phase-1 reader share
//            k>>5 == wave, so state writes are same-wave: 2 barriers/tick.
// Slot overwrite safety (parity 2, exact-tag): block X publishes tag t+1 only
// after consuming tag t from ALL slices (phase 3 of tick t-1), and any peer Z
// published tag t only after ITS phase-3 consumption of tag t-1. So when X
// overwrites tag t-1 -> t+1, every consumer of t-1 is already done.
// ---------------------------------------------------------------------------
__device__ __forceinline__ f32x4 pkfma4(float w, f32x4 h, f32x4 a) {
    f32x4 wv = {w, w, w, w};
    return __builtin_elementwise_fma(wv, h, a);
}
__device__ __forceinline__ int swz(int row, int kf) {    // kf multiple of 4
    return row * HID + (kf ^ ((row & 7) * 4));           // XOR 16B blocks
}
__device__ __forceinline__ u64 pload(const u64* p) {
    return __hip_atomic_load(p, __ATOMIC_RELAXED, __HIP_MEMORY_SCOPE_AGENT);
}

__launch_bounds__(1024)
__attribute__((amdgpu_waves_per_eu(4, 4)))
__global__ void rnn_fused3(const float* __restrict__ U0,   // (S,B,H) x@Wih0^T+biases
                           const float* __restrict__ Wt0,  // W_hh0^T [k][j]
                           const float* __restrict__ Wt1,  // W_hh1^T [k][j]
                           const float* __restrict__ Wih1, // W_ih1 (H,H) row-major
                           const float* __restrict__ bi1,
                           const float* __restrict__ bh1,
                           const float* __restrict__ hx,   // (2,B,H)
                           float* __restrict__ y1,         // (S,B,H) out
                           float* __restrict__ hT0,        // (B,H)
                           float* __restrict__ hT1,        // (B,H)
                           u64* __restrict__ hb)           // zeroed per launch
{
    __shared__ float Wih[JW * HID];                  // 64 KB swizzled [j][k^]
    __shared__ __align__(16) float scy[HID][NB];     // 8 KB: h0 state (tanh'd)
    __shared__ __align__(16) float sch[HID][NB];     // 8 KB: h1 state
    __shared__ __align__(16) f32x4 red0[32][33];     // ~17 KB padded partials
    __shared__ __align__(16) f32x4 redc[32][33];     // ~17 KB

    const int blk = blockIdx.x;
    const int g = blk & 15;              // group
    const int s = blk >> 4;              // slice 0..15
    const int j0 = s * JW;
    const int b0 = g * NB;
    const int tid = threadIdx.x;
    const int jl = tid & 63;
    const int kq = tid >> 6;             // wave 0..15
    const int j  = jl & 31;              // weight column within slice
    const int kh = jl >> 5;              // k-half
    const int kbase = kq * 32 + kh * 16; // 16-k range of this thread

    // ---- W_hh slices into registers (16 + 16 per thread) ----
    float w0r[16], w1r[16];
    #pragma unroll
    for (int kk = 0; kk < 16; ++kk) {
        w0r[kk] = Wt0[(size_t)(kbase + kk) * HID + j0 + j];
        w1r[kk] = Wt1[(size_t)(kbase + kk) * HID + j0 + j];
    }
    // ---- W_ih1 slice into swizzled LDS (16 floats per thread) ----
    #pragma unroll
    for (int i = 0; i < 4; ++i) {
        const int kf = kbase + 4 * i;
        float4 wv = *(const float4*)(Wih1 + (size_t)(j0 + j) * HID + kf);
        *(float4*)&Wih[swz(j, kf)] = wv;
    }

    // ---- poll identity: thread owns (k = kq*32 + jl/2, batches pb,pb+1) ----
    const int pk = kq * 32 + (jl >> 1);
    const int pb = 2 * (jl & 1);
    const size_t psl = ((size_t)g * SLICES + kq) * 128 + pb * 32 + (jl >> 1);

    // ---- init LDS state from hx (same-wave mapping as phase 3) ----
    {
        float2 a, c;
        a.x = hx[(size_t)(b0 + pb) * HID + pk];
        a.y = hx[(size_t)(b0 + pb + 1) * HID + pk];
        c.x = hx[(size_t)(BATCH + b0 + pb) * HID + pk];
        c.y = hx[(size_t)(BATCH + b0 + pb + 1) * HID + pk];
        *(float2*)&scy[pk][pb] = a;
        *(float2*)&sch[pk][pb] = c;
    }

    // ---- producer identity (waves 0-3) ----
    const bool isprod = (tid < 256);
    const int pl  = tid >> 7;            // 0: layer 0 (tid<128), 1: layer 1
    const int pj  = tid & 31;
    const int pbb = (tid >> 5) & 3;
    float bias1 = 0.f;
    if (isprod && pl == 1) bias1 = bi1[j0 + pj] + bh1[j0 + pj];
    __syncthreads();

    for (int t = 0; t <= SEQ; ++t) {
        const int p = (t + 1) & 1;
        const u32 tag = (u32)(t + 1);

        // producer prefetch of U0[t] (consumed after barrier A -> hidden)
        float u_cur = 0.f;
        if (isprod && pl == 0 && t < SEQ)
            u_cur = U0[((size_t)t * BATCH + (b0 + pbb)) * HID + j0 + pj];

        // ---- phase 1: partials over 16 k's x 4 batches ----
        f32x4 a0 = {0.f, 0.f, 0.f, 0.f};
        f32x4 ac = {0.f, 0.f, 0.f, 0.f};
        #pragma unroll
        for (int i = 0; i < 4; ++i) {
            const float4 wv = *(const float4*)&Wih[swz(j, kbase + 4 * i)];
            #pragma unroll
            for (int u = 0; u < 4; ++u) {
                const int k = kbase + 4 * i + u;
                const f32x4 hy = *(const f32x4*)&scy[k][0];   // broadcast read
                const f32x4 hh = *(const f32x4*)&sch[k][0];
                const float wi = (u == 0) ? wv.x : (u == 1) ? wv.y
                               : (u == 2) ? wv.z : wv.w;
                a0 = pkfma4(w0r[4 * i + u], hy, a0);
                ac = pkfma4(wi,             hy, ac);
                ac = pkfma4(w1r[4 * i + u], hh, ac);
            }
        }
        red0[2 * kq + kh][j] = a0;
        redc[2 * kq + kh][j] = ac;
        __syncthreads();   // A

        // ---- phase 2 (waves 0-3): reduce + publish pre-tanh + outputs ----
        if (isprod) {
            float sum = 0.f;
            if (pl == 0) {
                #pragma unroll
                for (int q = 0; q < 32; ++q)
                    sum += ((const float*)&red0[q][pj])[pbb];
                if (t < SEQ) {
                    const float pre = u_cur + sum;
                    const u64 pkt = ((u64)__float_as_uint(pre) << 32) | tag;
                    __hip_atomic_store(hb + p * PSTRIDE
                                          + ((size_t)g * SLICES + s) * 128 + pbb * 32 + pj,
                                       pkt, __ATOMIC_RELAXED, __HIP_MEMORY_SCOPE_AGENT);
                    if (t == SEQ - 1)
                        hT0[(size_t)(b0 + pbb) * HID + j0 + pj] = tanhf(pre);
                }
            } else {
                #pragma unroll
                for (int q = 0; q < 32; ++q)
                    sum += ((const float*)&redc[q][pj])[pbb];
                if (t >= 1) {
                    const float pre = bias1 + sum;
                    const float v = tanhf(pre);
                    y1[((size_t)(t - 1) * BATCH + (b0 + pbb)) * HID + j0 + pj] = v;
                    if (t < SEQ) {
                        const u64 pkt = ((u64)__float_as_uint(pre) << 32) | tag;
                        __hip_atomic_store(hb + SPACE + p * PSTRIDE
                                              + ((size_t)g * SLICES + s) * 128 + pbb * 32 + pj,
                                           pkt, __ATOMIC_RELAXED, __HIP_MEMORY_SCOPE_AGENT);
                    }
                    if (t == SEQ)
                        hT1[(size_t)(b0 + pbb) * HID + j0 + pj] = v;
                }
            }
        }
        __syncthreads();   // B

        // ---- phase 3: every thread polls its 4 packets (tag = flag) ----
        if (t < SEQ) {
            const u64* s0 = hb + p * PSTRIDE + psl;          // y0: (pk,pb),(pk,pb+1)
            const u64* s1 = hb + SPACE + p * PSTRIDE + psl;  // h1: same
            const bool need1 = (t >= 1);
            u64 k00 = 0, k01 = 0, k10 = 0, k11 = 0;
            bool d0 = false, d1 = false, d2 = !need1, d3 = !need1;
            int it = 0;
            do {
                if (!d0) { k00 = pload(s0);      d0 = ((u32)k00 == tag); }
                if (!d1) { k01 = pload(s0 + 32); d1 = ((u32)k01 == tag); }
                if (!d2) { k10 = pload(s1);      d2 = ((u32)k10 == tag); }
                if (!d3) { k11 = pload(s1 + 32); d3 = ((u32)k11 == tag); }
            } while (!(d0 && d1 && d2 && d3) && ++it < (1 << 15));  // no hang
            *(float2*)&scy[pk][pb] =
                make_float2(tanhf(__uint_as_float((u32)(k00 >> 32))),
                            tanhf(__uint_as_float((u32)(k01 >> 32))));
            if (need1)
                *(float2*)&sch[pk][pb] =
                    make_float2(tanhf(__uint_as_float((u32)(k10 >> 32))),
                                tanhf(__uint_as_float((u32)(k11 >> 32))));
        }
    }
}

// ---------------------------------------------------------------------------
// Launch
// ---------------------------------------------------------------------------
extern "C" void kernel_launch(void* const* d_in, const int* in_sizes, int n_in,
                              void* d_out, int out_size, void* d_ws, size_t ws_size,
                              hipStream_t stream) {
    (void)in_sizes; (void)n_in; (void)out_size; (void)ws_size;

    const float* x      = (const float*)d_in[0];   // (S,B,I)
    const float* hx     = (const float*)d_in[1];   // (2,B,H)
    const float* W_ih0  = (const float*)d_in[2];   // (H,I)
    const float* W_hh0  = (const float*)d_in[3];   // (H,H)
    const float* b_ih0  = (const float*)d_in[4];   // (H,)
    const float* b_hh0  = (const float*)d_in[5];   // (H,)
    const float* W_ih1  = (const float*)d_in[6];   // (H,H)
    const float* W_hh1  = (const float*)d_in[7];   // (H,H)
    const float* b_ih1  = (const float*)d_in[8];   // (H,)
    const float* b_hh1  = (const float*)d_in[9];   // (H,)

    float* out = (float*)d_out;
    float* y1   = out;                                  // (S,B,H)
    float* hT0  = out + (size_t)SEQ * BATCH * HID;      // (B,H)
    float* hT1  = hT0 + (size_t)BATCH * HID;            // (B,H)

    // Workspace: Wt0 (1MB) | Wt1 (1MB) | hb (1MB) | U0 (128MB)
    float* Wt0 = (float*)d_ws;
    float* Wt1 = Wt0 + (size_t)HID * HID;
    u64* hb = (u64*)(Wt1 + (size_t)HID * HID);
    float* U0 = (float*)(hb + 2 * SPACE);

    // zero both slot spaces every launch (tag 0 never matches; agent-scope
    // stores write through -> no stale dirty-line ABA across timed runs)
    hipMemsetAsync(hb, 0, 2 * SPACE * sizeof(u64), stream);

    // 1. transpose W_hh for both layers
    transposeW<<<256, 256, 0, stream>>>(W_hh0, Wt0);
    transposeW<<<256, 256, 0, stream>>>(W_hh1, Wt1);

    // 2. Layer 0 input GEMM: U0 = x @ W_ih0^T + b_ih0 + b_hh0
    gemm_bias<<<(MROWS / BM) * (HID / BN), 256, 0, stream>>>(x, W_ih0, b_ih0, b_hh0, U0);

    // 3. Fused dual-layer recurrence (y0 never hits HBM; no layer-1 GEMM)
    rnn_fused3<<<NGROUPS * SLICES, 1024, 0, stream>>>(
        U0, Wt0, Wt1, W_ih1, b_ih1, b_hh1, hx, y1, hT0, hT1, hb);
}